// Round 18
// baseline (650.100 us; speedup 1.0000x reference)
//
#include <hip/hip_runtime.h>

typedef unsigned short ushort_t;
typedef short short8 __attribute__((ext_vector_type(8)));
typedef float f32x4 __attribute__((ext_vector_type(4)));

#define M_TOT 16384
#define N_TOT 4096
#define K_TOT 4096

// ---------------- helpers ----------------

__device__ __forceinline__ unsigned short f2bf(float f) {
  unsigned int u = __float_as_uint(f);
  unsigned int r = (u + 0x7fffu + ((u >> 16) & 1u)) >> 16;  // RNE
  return (unsigned short)r;
}

__device__ __forceinline__ void gld_lds16(const void* g, void* l) {
  __builtin_amdgcn_global_load_lds(
      (__attribute__((address_space(1))) const unsigned int*)g,
      (__attribute__((address_space(3))) unsigned int*)l, 16, 0, 0);
}

// ---------------- fused aux: X->bf16 + h (blocks 0..1023), W->bf16 (1024..1535) ----------------
// x-part v2: LANE-CONTIGUOUS addressing — every load instruction covers one
// contiguous 1KB segment (addr = it*1024 + q*256 + lane*4), every xb write a
// contiguous 512B segment. Fixes the 64B-lane-stride scatter of the old form.

__global__ __launch_bounds__(256) void aux_kernel(
    const float* __restrict__ x, const float* __restrict__ base_w,
    const float* __restrict__ lora_a, ushort_t* __restrict__ xb,
    ushort_t* __restrict__ wb, float* __restrict__ h) {
  const int tid = threadIdx.x;
  if (blockIdx.x >= 1024) {
    const int wblk = blockIdx.x - 1024;
    const float4* src = (const float4*)base_w + (size_t)wblk * 8192;
    uint4* dst = (uint4*)wb + (size_t)wblk * 4096;
#pragma unroll 4
    for (int j = 0; j < 16; ++j) {
      int p = j * 256 + tid;
      float4 a = src[p * 2], b = src[p * 2 + 1];
      union { ushort_t u[8]; uint4 v; } o;
      o.u[0] = f2bf(a.x); o.u[1] = f2bf(a.y); o.u[2] = f2bf(a.z); o.u[3] = f2bf(a.w);
      o.u[4] = f2bf(b.x); o.u[5] = f2bf(b.y); o.u[6] = f2bf(b.z); o.u[7] = f2bf(b.w);
      dst[p] = o.v;
    }
    return;
  }
  // X part: 16 rows/block, 4 rows/wave
  const int lane = tid & 63;
  const int wave = tid >> 6;
  const int rowBase = blockIdx.x * 16 + wave * 4;  // 16 | 1024: no group crossing
  const int g = rowBase >> 10;
  const float* A = lora_a + (size_t)g * 16 * K_TOT;

  float acc[4][16] = {};
#pragma unroll 1
  for (int it4 = 0; it4 < 4; ++it4) {
    const int base = it4 * 1024 + lane * 4;
    float4 xv[4][4];
#pragma unroll
    for (int r = 0; r < 4; ++r) {
      const float* xr = x + (size_t)(rowBase + r) * K_TOT + base;
      ushort_t* xo = xb + (size_t)(rowBase + r) * K_TOT + base;
#pragma unroll
      for (int q = 0; q < 4; ++q) {
        xv[r][q] = *(const float4*)(xr + q * 256);
        union { ushort_t u[4]; uint2 d; } o;
        o.u[0] = f2bf(xv[r][q].x); o.u[1] = f2bf(xv[r][q].y);
        o.u[2] = f2bf(xv[r][q].z); o.u[3] = f2bf(xv[r][q].w);
        *(uint2*)(xo + q * 256) = o.d;
      }
    }
#pragma unroll
    for (int t = 0; t < 16; ++t) {
      const float* Ar = A + (size_t)t * K_TOT + base;
#pragma unroll
      for (int q = 0; q < 4; ++q) {
        float4 av = *(const float4*)(Ar + q * 256);
#pragma unroll
        for (int r = 0; r < 4; ++r)
          acc[r][t] += xv[r][q].x * av.x + xv[r][q].y * av.y +
                       xv[r][q].z * av.z + xv[r][q].w * av.w;
      }
    }
  }
#pragma unroll
  for (int r = 0; r < 4; ++r)
#pragma unroll
    for (int t = 0; t < 16; ++t) {
      float v = acc[r][t];
      v += __shfl_xor(v, 32); v += __shfl_xor(v, 16); v += __shfl_xor(v, 8);
      v += __shfl_xor(v, 4);  v += __shfl_xor(v, 2);  v += __shfl_xor(v, 1);
      if (lane == 0) {
        int mloc = (rowBase + r) & 1023;
        h[((size_t)g << 14) + (size_t)mloc * 16 + t] = v;
      }
    }
}

// ---------------- main GEMM: out = Xbf*Wbf^T + bias + h*lb^T ----------------
// r12/r14/r16 schedule (best: 467-478us, MfmaUtil 54-55%): 256x256 tile, BK=64,
// 8 waves (2Mx4N), 16x16x32 MFMA, 8-phase register-pipelined ds_reads, single
// end-barrier per phase except P4/P8 (trailing barrier removed); VMCNT(4)+BAR
// confirms at P4/P8 only. Epilogue: f32x4 hv loads.

#define STAGE_A(kt, buf, hh) do {                                              \
    const ushort_t* _g = aBase + (size_t)((hh) * 128) * K_TOT + (size_t)(kt) * 64; \
    gld_lds16(_g, &lds[(buf) * 16384 + (hh) * 8192 + wave * 512]);             \
    gld_lds16(_g + (size_t)64 * K_TOT,                                         \
              &lds[(buf) * 16384 + (hh) * 8192 + 4096 + wave * 512]);          \
  } while (0)
#define STAGE_B(kt, buf, hh) do {                                              \
    const ushort_t* _g = bBase + (size_t)((hh) * 128) * K_TOT + (size_t)(kt) * 64; \
    gld_lds16(_g, &lds[32768 + (buf) * 16384 + (hh) * 8192 + wave * 512]);     \
    gld_lds16(_g + (size_t)64 * K_TOT,                                         \
              &lds[32768 + (buf) * 16384 + (hh) * 8192 + 4096 + wave * 512]);  \
  } while (0)

#define LDA_TO(dst, buf, mh) do {                                              \
    _Pragma("unroll") for (int mf = 0; mf < 4; ++mf)                           \
    _Pragma("unroll") for (int kk = 0; kk < 2; ++kk)                           \
      dst[mf][kk] = *(const short8*)(ldsc + (buf) * 32768 + wm * 16384 +       \
                                     (mh) * 8192 + mf * 2048 + frB +           \
                                     (eA ^ (kk << 6)));                        \
  } while (0)
#define LDB_TO(dst, buf, nh) do {                                              \
    _Pragma("unroll") for (int nf = 0; nf < 2; ++nf)                           \
    _Pragma("unroll") for (int kk = 0; kk < 2; ++kk)                           \
      dst[nf][kk] = *(const short8*)(ldsc + 65536 + (buf) * 32768 +            \
                                     wn * 8192 + (nh) * 4096 + nf * 2048 +     \
                                     frB + (eA ^ (kk << 6)));                  \
  } while (0)

#define QUADR(ar, br, mh, nh) do {                                             \
    __builtin_amdgcn_s_setprio(1);                                             \
    _Pragma("unroll") for (int kk = 0; kk < 2; ++kk)                           \
    _Pragma("unroll") for (int mf = 0; mf < 4; ++mf)                           \
    _Pragma("unroll") for (int nf = 0; nf < 2; ++nf)                           \
      acc[(mh) * 4 + mf][(nh) * 2 + nf] = __builtin_amdgcn_mfma_f32_16x16x32_bf16( \
          ar[mf][kk], br[nf][kk], acc[(mh) * 4 + mf][(nh) * 2 + nf], 0, 0, 0); \
    __builtin_amdgcn_s_setprio(0);                                             \
  } while (0)

#define BAR __builtin_amdgcn_s_barrier()
#define VMCNT(n) asm volatile("s_waitcnt vmcnt(" #n ")" ::: "memory")
#define LGKM(n) asm volatile("s_waitcnt lgkmcnt(" #n ")" ::: "memory")

__global__ __launch_bounds__(512, 2) void gemm_kernel(
    const ushort_t* __restrict__ xb,    // [M][K] bf16
    const ushort_t* __restrict__ wb,    // [N][K] bf16
    const float* __restrict__ bias,     // [N]
    const float* __restrict__ hbuf,     // [16][1024][16] fp32
    const float* __restrict__ lorab,    // [16][4096][16] fp32
    float* __restrict__ out) {          // [M][N] fp32
  __shared__ __align__(16) ushort_t lds[65536];  // 128 KiB

  const int tid = threadIdx.x;
  const int lane = tid & 63;
  const int wave = tid >> 6;
  const int wm = wave >> 2;             // 0..1
  const int wn = wave & 3;              // 0..3
  const int bid = blockIdx.x;
  const int xcd = bid & 7;
  const int j = bid >> 3;               // 0..127
  const int by = xcd * 8 + (j & 7);     // 0..63
  const int bx = j >> 3;                // 0..15
  const int rowBase = by * 256;
  const int colBase = bx * 256;

  const int srow = lane >> 3;
  const int scol = ((lane & 7) ^ srow) << 3;     // inverse-swizzled global col
  const ushort_t* aBase = xb + (size_t)(rowBase + wave * 8 + srow) * K_TOT + scol;
  const ushort_t* bBase = wb + (size_t)(colBase + wave * 8 + srow) * K_TOT + scol;

  const int fr = lane & 15;
  const int fg = lane >> 4;
  const int eA = (fg << 4) ^ ((fr & 7) << 4);
  const int frB = fr * 128;
  const char* ldsc = (const char*)lds;

  f32x4 acc[8][4] = {};
  short8 aR0[4][2], aR1[4][2];            // A m-half slots
  short8 b0a[2][2], b0b[2][2], b1a[2][2], b1b[2][2];  // B (buf, n-half) slots

  // ---- prologue: stage K0 + B(K1); confirm K0; BAR; read Q1 operands ----
  STAGE_A(0, 0, 0); STAGE_A(0, 0, 1);
  STAGE_B(0, 0, 0); STAGE_B(0, 0, 1);
  STAGE_B(1, 1, 0); STAGE_B(1, 1, 1);
  VMCNT(4);
  BAR;
  LDA_TO(aR0, 0, 0); LDB_TO(b0a, 0, 0);

  for (int it = 0; it < 32; ++it) {
    const int k1 = 2 * it + 1;          // <= 63, no wrap
    const int k2 = (2 * it + 2) & 63;   // last iter: staged, never read
    const int k3 = (2 * it + 3) & 63;
    // P1: Q1=(buf0,m0,n0); read b0b for Q2; stage A(T+1)h0
    LDB_TO(b0b, 0, 1);
    STAGE_A(k1, 1, 0);
    LGKM(4); QUADR(aR0, b0a, 0, 0); BAR;
    // P2: Q2=(buf0,m0,n1); read aR1(buf0,m1) for Q3; stage A(T+1)h1
    LDA_TO(aR1, 0, 1);
    STAGE_A(k1, 1, 1);
    LGKM(8); QUADR(aR0, b0b, 0, 1); BAR;
    // P3: Q3=(buf0,m1,n1); stage B(T+2)h0
    STAGE_B(k2, 0, 0);
    LGKM(0); QUADR(aR1, b0b, 1, 1); BAR;
    // P4: Q4=(buf0,m1,n0); stage B(T+2)h1; confirm tile T+1; reads for Q5 after
    //     the confirm BAR. Trailing barrier removed (P4/P5 regions disjoint).
    STAGE_B(k2, 0, 1);
    VMCNT(4);
    BAR;
    LDA_TO(aR0, 1, 0); LDB_TO(b1a, 1, 0);
    LGKM(12); QUADR(aR1, b0a, 1, 0);
    // P5: Q5=(buf1,m0,n0); read b1b for Q6; stage A(T+2)h0
    LDB_TO(b1b, 1, 1);
    STAGE_A(k2, 0, 0);
    LGKM(4); QUADR(aR0, b1a, 0, 0); BAR;
    // P6: Q6=(buf1,m0,n1); read aR1(buf1,m1) for Q7; stage A(T+2)h1
    LDA_TO(aR1, 1, 1);
    STAGE_A(k2, 0, 1);
    LGKM(8); QUADR(aR0, b1b, 0, 1); BAR;
    // P7: Q7=(buf1,m1,n1); stage B(T+3)h0
    STAGE_B(k3, 1, 0);
    LGKM(0); QUADR(aR1, b1b, 1, 1); BAR;
    // P8: Q8=(buf1,m1,n0); stage B(T+3)h1; confirm tile T+2; reads for next Q1.
    //     Trailing barrier removed.
    STAGE_B(k3, 1, 1);
    VMCNT(4);
    BAR;
    LDA_TO(aR0, 0, 0); LDB_TO(b0a, 0, 0);
    LGKM(12); QUADR(aR1, b1a, 1, 0);
  }

  // ---- epilogue: drain everything before repurposing LDS ----
  asm volatile("s_waitcnt vmcnt(0) lgkmcnt(0)" ::: "memory");
  BAR;

  float* hs = (float*)lds;          // [256][16] fp32
  float* lbs = hs + 4096;           // [256][16] fp32
  {
    const int g = by >> 2;
    const float* hsrc = hbuf + ((size_t)g * 1024 + (size_t)(by & 3) * 256) * 16;
    const float* lsrc = lorab + ((size_t)g * 4096 + (size_t)colBase) * 16;
    for (int idx = tid; idx < 1024; idx += 512) {
      ((float4*)hs)[idx] = ((const float4*)hsrc)[idx];
      ((float4*)lbs)[idx] = ((const float4*)lsrc)[idx];
    }
  }
  __syncthreads();

  float lbv[4][16];
  float bv[4];
#pragma unroll
  for (int nh = 0; nh < 2; ++nh)
#pragma unroll
    for (int nf = 0; nf < 2; ++nf) {
      const int cl = wn * 64 + nh * 32 + nf * 16 + fr;
      bv[nh * 2 + nf] = bias[colBase + cl];
#pragma unroll
      for (int r = 0; r < 16; ++r) lbv[nh * 2 + nf][r] = lbs[cl * 16 + r];
    }

#pragma unroll
  for (int mh = 0; mh < 2; ++mh)
#pragma unroll
    for (int mf = 0; mf < 4; ++mf)
#pragma unroll
      for (int i = 0; i < 4; ++i) {
        const int rl = wm * 128 + mh * 64 + mf * 16 + fg * 4 + i;
        f32x4 hv4[4];
#pragma unroll
        for (int q = 0; q < 4; ++q)
          hv4[q] = *(const f32x4*)(hs + (size_t)rl * 16 + q * 4);
        float* orow = out + (size_t)(rowBase + rl) * N_TOT + colBase;
#pragma unroll
        for (int nh = 0; nh < 2; ++nh)
#pragma unroll
          for (int nf = 0; nf < 2; ++nf) {
            float d = 0.f;
#pragma unroll
            for (int q = 0; q < 4; ++q)
#pragma unroll
              for (int e = 0; e < 4; ++e)
                d += hv4[q][e] * lbv[nh * 2 + nf][q * 4 + e];
            orow[wn * 64 + nh * 32 + nf * 16 + fr] =
                acc[mh * 4 + mf][nh * 2 + nf][i] + bv[nh * 2 + nf] + d;
          }
      }
}

// ---------------- launch ----------------

extern "C" void kernel_launch(void* const* d_in, const int* in_sizes, int n_in,
                              void* d_out, int out_size, void* d_ws, size_t ws_size,
                              hipStream_t stream) {
  const float* x      = (const float*)d_in[0];  // [16384][4096]
  const float* base_w = (const float*)d_in[1];  // [4096][4096]
  const float* base_b = (const float*)d_in[2];  // [4096]
  const float* lora_a = (const float*)d_in[3];  // [16][16][4096]
  const float* lora_b = (const float*)d_in[4];  // [16][4096][16]
  float* out = (float*)d_out;

  // workspace: h (1MB) | w_bf16 (32MB) | x_bf16 (128MB)
  char* ws = (char*)d_ws;
  float* h = (float*)ws;
  ushort_t* wb = (ushort_t*)(ws + (1u << 20));
  ushort_t* xb = (ushort_t*)(ws + (1u << 20) + (32u << 20));

  aux_kernel<<<1536, 256, 0, stream>>>(x, base_w, lora_a, xb, wb, h);
  gemm_kernel<<<1024, 512, 0, stream>>>(xb, wb, base_b, h, lora_b, out);
}

// Round 19
// 600.739 us; speedup vs baseline: 1.0822x; 1.0822x over previous
//
#include <hip/hip_runtime.h>

typedef unsigned short ushort_t;
typedef short short8 __attribute__((ext_vector_type(8)));
typedef float f32x4 __attribute__((ext_vector_type(4)));

#define M_TOT 16384
#define N_TOT 4096
#define K_TOT 4096

// ---------------- helpers ----------------

__device__ __forceinline__ unsigned short f2bf(float f) {
  unsigned int u = __float_as_uint(f);
  unsigned int r = (u + 0x7fffu + ((u >> 16) & 1u)) >> 16;  // RNE
  return (unsigned short)r;
}

__device__ __forceinline__ void gld_lds16(const void* g, void* l) {
  __builtin_amdgcn_global_load_lds(
      (__attribute__((address_space(1))) const unsigned int*)g,
      (__attribute__((address_space(3))) unsigned int*)l, 16, 0, 0);
}

// ---------------- fused aux: X->bf16 + h (blocks 0..1023), W->bf16 (1024..1535) ----------------
// r16 form (best measured: ~125us). 16 rows/block, 4 rows/wave, 16 elems/lane
// (64B loads, 2x uint4 stores); q-loads jointly cover a contiguous 4KB span.

__global__ __launch_bounds__(256) void aux_kernel(
    const float* __restrict__ x, const float* __restrict__ base_w,
    const float* __restrict__ lora_a, ushort_t* __restrict__ xb,
    ushort_t* __restrict__ wb, float* __restrict__ h) {
  const int tid = threadIdx.x;
  if (blockIdx.x >= 1024) {
    const int wblk = blockIdx.x - 1024;
    const float4* src = (const float4*)base_w + (size_t)wblk * 8192;
    uint4* dst = (uint4*)wb + (size_t)wblk * 4096;
#pragma unroll 4
    for (int j = 0; j < 16; ++j) {
      int p = j * 256 + tid;
      float4 a = src[p * 2], b = src[p * 2 + 1];
      union { ushort_t u[8]; uint4 v; } o;
      o.u[0] = f2bf(a.x); o.u[1] = f2bf(a.y); o.u[2] = f2bf(a.z); o.u[3] = f2bf(a.w);
      o.u[4] = f2bf(b.x); o.u[5] = f2bf(b.y); o.u[6] = f2bf(b.z); o.u[7] = f2bf(b.w);
      dst[p] = o.v;
    }
    return;
  }
  // X part: 16 rows/block, 4 rows/wave, 16 elems/lane
  const int lane = tid & 63;
  const int wave = tid >> 6;
  const int rowBase = blockIdx.x * 16 + wave * 4;  // 16 | 1024: no group crossing
  const int g = rowBase >> 10;
  const float* A = lora_a + (size_t)g * 16 * K_TOT;

  float acc[4][16] = {};
  for (int i = lane * 16; i < K_TOT; i += 1024) {   // 4 iterations
    float4 xv[4][4];
#pragma unroll
    for (int r = 0; r < 4; ++r) {
      const float* xr = x + (size_t)(rowBase + r) * K_TOT + i;
#pragma unroll
      for (int q = 0; q < 4; ++q) xv[r][q] = *(const float4*)(xr + q * 4);
      union { ushort_t u[8]; uint4 v; } o0, o1;
      o0.u[0] = f2bf(xv[r][0].x); o0.u[1] = f2bf(xv[r][0].y);
      o0.u[2] = f2bf(xv[r][0].z); o0.u[3] = f2bf(xv[r][0].w);
      o0.u[4] = f2bf(xv[r][1].x); o0.u[5] = f2bf(xv[r][1].y);
      o0.u[6] = f2bf(xv[r][1].z); o0.u[7] = f2bf(xv[r][1].w);
      o1.u[0] = f2bf(xv[r][2].x); o1.u[1] = f2bf(xv[r][2].y);
      o1.u[2] = f2bf(xv[r][2].z); o1.u[3] = f2bf(xv[r][2].w);
      o1.u[4] = f2bf(xv[r][3].x); o1.u[5] = f2bf(xv[r][3].y);
      o1.u[6] = f2bf(xv[r][3].z); o1.u[7] = f2bf(xv[r][3].w);
      ushort_t* xo = xb + (size_t)(rowBase + r) * K_TOT + i;
      *(uint4*)xo = o0.v;
      *(uint4*)(xo + 8) = o1.v;
    }
#pragma unroll
    for (int t = 0; t < 16; ++t) {
      const float* Ar = A + (size_t)t * K_TOT + i;
      float4 a0 = *(const float4*)Ar;
      float4 a1 = *(const float4*)(Ar + 4);
      float4 a2 = *(const float4*)(Ar + 8);
      float4 a3 = *(const float4*)(Ar + 12);
#pragma unroll
      for (int r = 0; r < 4; ++r)
        acc[r][t] += xv[r][0].x * a0.x + xv[r][0].y * a0.y + xv[r][0].z * a0.z + xv[r][0].w * a0.w +
                     xv[r][1].x * a1.x + xv[r][1].y * a1.y + xv[r][1].z * a1.z + xv[r][1].w * a1.w +
                     xv[r][2].x * a2.x + xv[r][2].y * a2.y + xv[r][2].z * a2.z + xv[r][2].w * a2.w +
                     xv[r][3].x * a3.x + xv[r][3].y * a3.y + xv[r][3].z * a3.z + xv[r][3].w * a3.w;
    }
  }
#pragma unroll
  for (int r = 0; r < 4; ++r)
#pragma unroll
    for (int t = 0; t < 16; ++t) {
      float v = acc[r][t];
      v += __shfl_xor(v, 32); v += __shfl_xor(v, 16); v += __shfl_xor(v, 8);
      v += __shfl_xor(v, 4);  v += __shfl_xor(v, 2);  v += __shfl_xor(v, 1);
      if (lane == 0) {
        int mloc = (rowBase + r) & 1023;
        h[((size_t)g << 14) + (size_t)mloc * 16 + t] = v;
      }
    }
}

// ---------------- main GEMM: out = Xbf*Wbf^T + bias + h*lb^T ----------------
// r12/r14/r16 schedule (best: 467-478us, MfmaUtil 54-56%): 256x256 tile, BK=64,
// 8 waves (2Mx4N), 16x16x32 MFMA, 8-phase register-pipelined ds_reads, single
// end-barrier per phase except P4/P8 (trailing barrier removed); VMCNT(4)+BAR
// confirms at P4/P8 only. Epilogue: f32x4 hv loads, fused bias + h*lb^T.

#define STAGE_A(kt, buf, hh) do {                                              \
    const ushort_t* _g = aBase + (size_t)((hh) * 128) * K_TOT + (size_t)(kt) * 64; \
    gld_lds16(_g, &lds[(buf) * 16384 + (hh) * 8192 + wave * 512]);             \
    gld_lds16(_g + (size_t)64 * K_TOT,                                         \
              &lds[(buf) * 16384 + (hh) * 8192 + 4096 + wave * 512]);          \
  } while (0)
#define STAGE_B(kt, buf, hh) do {                                              \
    const ushort_t* _g = bBase + (size_t)((hh) * 128) * K_TOT + (size_t)(kt) * 64; \
    gld_lds16(_g, &lds[32768 + (buf) * 16384 + (hh) * 8192 + wave * 512]);     \
    gld_lds16(_g + (size_t)64 * K_TOT,                                         \
              &lds[32768 + (buf) * 16384 + (hh) * 8192 + 4096 + wave * 512]);  \
  } while (0)

#define LDA_TO(dst, buf, mh) do {                                              \
    _Pragma("unroll") for (int mf = 0; mf < 4; ++mf)                           \
    _Pragma("unroll") for (int kk = 0; kk < 2; ++kk)                           \
      dst[mf][kk] = *(const short8*)(ldsc + (buf) * 32768 + wm * 16384 +       \
                                     (mh) * 8192 + mf * 2048 + frB +           \
                                     (eA ^ (kk << 6)));                        \
  } while (0)
#define LDB_TO(dst, buf, nh) do {                                              \
    _Pragma("unroll") for (int nf = 0; nf < 2; ++nf)                           \
    _Pragma("unroll") for (int kk = 0; kk < 2; ++kk)                           \
      dst[nf][kk] = *(const short8*)(ldsc + 65536 + (buf) * 32768 +            \
                                     wn * 8192 + (nh) * 4096 + nf * 2048 +     \
                                     frB + (eA ^ (kk << 6)));                  \
  } while (0)

#define QUADR(ar, br, mh, nh) do {                                             \
    __builtin_amdgcn_s_setprio(1);                                             \
    _Pragma("unroll") for (int kk = 0; kk < 2; ++kk)                           \
    _Pragma("unroll") for (int mf = 0; mf < 4; ++mf)                           \
    _Pragma("unroll") for (int nf = 0; nf < 2; ++nf)                           \
      acc[(mh) * 4 + mf][(nh) * 2 + nf] = __builtin_amdgcn_mfma_f32_16x16x32_bf16( \
          ar[mf][kk], br[nf][kk], acc[(mh) * 4 + mf][(nh) * 2 + nf], 0, 0, 0); \
    __builtin_amdgcn_s_setprio(0);                                             \
  } while (0)

#define BAR __builtin_amdgcn_s_barrier()
#define VMCNT(n) asm volatile("s_waitcnt vmcnt(" #n ")" ::: "memory")
#define LGKM(n) asm volatile("s_waitcnt lgkmcnt(" #n ")" ::: "memory")

__global__ __launch_bounds__(512, 2) void gemm_kernel(
    const ushort_t* __restrict__ xb,    // [M][K] bf16
    const ushort_t* __restrict__ wb,    // [N][K] bf16
    const float* __restrict__ bias,     // [N]
    const float* __restrict__ hbuf,     // [16][1024][16] fp32
    const float* __restrict__ lorab,    // [16][4096][16] fp32
    float* __restrict__ out) {          // [M][N] fp32
  __shared__ __align__(16) ushort_t lds[65536];  // 128 KiB

  const int tid = threadIdx.x;
  const int lane = tid & 63;
  const int wave = tid >> 6;
  const int wm = wave >> 2;             // 0..1
  const int wn = wave & 3;              // 0..3
  const int bid = blockIdx.x;
  const int xcd = bid & 7;
  const int j = bid >> 3;               // 0..127
  const int by = xcd * 8 + (j & 7);     // 0..63
  const int bx = j >> 3;                // 0..15
  const int rowBase = by * 256;
  const int colBase = bx * 256;

  const int srow = lane >> 3;
  const int scol = ((lane & 7) ^ srow) << 3;     // inverse-swizzled global col
  const ushort_t* aBase = xb + (size_t)(rowBase + wave * 8 + srow) * K_TOT + scol;
  const ushort_t* bBase = wb + (size_t)(colBase + wave * 8 + srow) * K_TOT + scol;

  const int fr = lane & 15;
  const int fg = lane >> 4;
  const int eA = (fg << 4) ^ ((fr & 7) << 4);
  const int frB = fr * 128;
  const char* ldsc = (const char*)lds;

  f32x4 acc[8][4] = {};
  short8 aR0[4][2], aR1[4][2];            // A m-half slots
  short8 b0a[2][2], b0b[2][2], b1a[2][2], b1b[2][2];  // B (buf, n-half) slots

  // ---- prologue: stage K0 + B(K1); confirm K0; BAR; read Q1 operands ----
  STAGE_A(0, 0, 0); STAGE_A(0, 0, 1);
  STAGE_B(0, 0, 0); STAGE_B(0, 0, 1);
  STAGE_B(1, 1, 0); STAGE_B(1, 1, 1);
  VMCNT(4);
  BAR;
  LDA_TO(aR0, 0, 0); LDB_TO(b0a, 0, 0);

  for (int it = 0; it < 32; ++it) {
    const int k1 = 2 * it + 1;          // <= 63, no wrap
    const int k2 = (2 * it + 2) & 63;   // last iter: staged, never read
    const int k3 = (2 * it + 3) & 63;
    // P1: Q1=(buf0,m0,n0); read b0b for Q2; stage A(T+1)h0
    LDB_TO(b0b, 0, 1);
    STAGE_A(k1, 1, 0);
    LGKM(4); QUADR(aR0, b0a, 0, 0); BAR;
    // P2: Q2=(buf0,m0,n1); read aR1(buf0,m1) for Q3; stage A(T+1)h1
    LDA_TO(aR1, 0, 1);
    STAGE_A(k1, 1, 1);
    LGKM(8); QUADR(aR0, b0b, 0, 1); BAR;
    // P3: Q3=(buf0,m1,n1); stage B(T+2)h0
    STAGE_B(k2, 0, 0);
    LGKM(0); QUADR(aR1, b0b, 1, 1); BAR;
    // P4: Q4=(buf0,m1,n0); stage B(T+2)h1; confirm tile T+1; reads for Q5 after
    //     the confirm BAR. Trailing barrier removed (P4/P5 regions disjoint).
    STAGE_B(k2, 0, 1);
    VMCNT(4);
    BAR;
    LDA_TO(aR0, 1, 0); LDB_TO(b1a, 1, 0);
    LGKM(12); QUADR(aR1, b0a, 1, 0);
    // P5: Q5=(buf1,m0,n0); read b1b for Q6; stage A(T+2)h0
    LDB_TO(b1b, 1, 1);
    STAGE_A(k2, 0, 0);
    LGKM(4); QUADR(aR0, b1a, 0, 0); BAR;
    // P6: Q6=(buf1,m0,n1); read aR1(buf1,m1) for Q7; stage A(T+2)h1
    LDA_TO(aR1, 1, 1);
    STAGE_A(k2, 0, 1);
    LGKM(8); QUADR(aR0, b1b, 0, 1); BAR;
    // P7: Q7=(buf1,m1,n1); stage B(T+3)h0
    STAGE_B(k3, 1, 0);
    LGKM(0); QUADR(aR1, b1b, 1, 1); BAR;
    // P8: Q8=(buf1,m1,n0); stage B(T+3)h1; confirm tile T+2; reads for next Q1.
    //     Trailing barrier removed.
    STAGE_B(k3, 1, 1);
    VMCNT(4);
    BAR;
    LDA_TO(aR0, 0, 0); LDB_TO(b0a, 0, 0);
    LGKM(12); QUADR(aR1, b1a, 1, 0);
  }

  // ---- epilogue: drain everything before repurposing LDS ----
  asm volatile("s_waitcnt vmcnt(0) lgkmcnt(0)" ::: "memory");
  BAR;

  float* hs = (float*)lds;          // [256][16] fp32
  float* lbs = hs + 4096;           // [256][16] fp32
  {
    const int g = by >> 2;
    const float* hsrc = hbuf + ((size_t)g * 1024 + (size_t)(by & 3) * 256) * 16;
    const float* lsrc = lorab + ((size_t)g * 4096 + (size_t)colBase) * 16;
    for (int idx = tid; idx < 1024; idx += 512) {
      ((float4*)hs)[idx] = ((const float4*)hsrc)[idx];
      ((float4*)lbs)[idx] = ((const float4*)lsrc)[idx];
    }
  }
  __syncthreads();

  float lbv[4][16];
  float bv[4];
#pragma unroll
  for (int nh = 0; nh < 2; ++nh)
#pragma unroll
    for (int nf = 0; nf < 2; ++nf) {
      const int cl = wn * 64 + nh * 32 + nf * 16 + fr;
      bv[nh * 2 + nf] = bias[colBase + cl];
#pragma unroll
      for (int r = 0; r < 16; ++r) lbv[nh * 2 + nf][r] = lbs[cl * 16 + r];
    }

#pragma unroll
  for (int mh = 0; mh < 2; ++mh)
#pragma unroll
    for (int mf = 0; mf < 4; ++mf)
#pragma unroll
      for (int i = 0; i < 4; ++i) {
        const int rl = wm * 128 + mh * 64 + mf * 16 + fg * 4 + i;
        f32x4 hv4[4];
#pragma unroll
        for (int q = 0; q < 4; ++q)
          hv4[q] = *(const f32x4*)(hs + (size_t)rl * 16 + q * 4);
        float* orow = out + (size_t)(rowBase + rl) * N_TOT + colBase;
#pragma unroll
        for (int nh = 0; nh < 2; ++nh)
#pragma unroll
          for (int nf = 0; nf < 2; ++nf) {
            float d = 0.f;
#pragma unroll
            for (int q = 0; q < 4; ++q)
#pragma unroll
              for (int e = 0; e < 4; ++e)
                d += hv4[q][e] * lbv[nh * 2 + nf][q * 4 + e];
            orow[wn * 64 + nh * 32 + nf * 16 + fr] =
                acc[mh * 4 + mf][nh * 2 + nf][i] + bv[nh * 2 + nf] + d;
          }
      }
}

// ---------------- launch ----------------

extern "C" void kernel_launch(void* const* d_in, const int* in_sizes, int n_in,
                              void* d_out, int out_size, void* d_ws, size_t ws_size,
                              hipStream_t stream) {
  const float* x      = (const float*)d_in[0];  // [16384][4096]
  const float* base_w = (const float*)d_in[1];  // [4096][4096]
  const float* base_b = (const float*)d_in[2];  // [4096]
  const float* lora_a = (const float*)d_in[3];  // [16][16][4096]
  const float* lora_b = (const float*)d_in[4];  // [16][4096][16]
  float* out = (float*)d_out;

  // workspace: h (1MB) | w_bf16 (32MB) | x_bf16 (128MB)
  char* ws = (char*)d_ws;
  float* h = (float*)ws;
  ushort_t* wb = (ushort_t*)(ws + (1u << 20));
  ushort_t* xb = (ushort_t*)(ws + (1u << 20) + (32u << 20));

  aux_kernel<<<1536, 256, 0, stream>>>(x, base_w, lora_a, xb, wb, h);
  gemm_kernel<<<1024, 512, 0, stream>>>(xb, wb, base_b, h, lora_b, out);
}